// Round 10
// baseline (720.744 us; speedup 1.0000x reference)
//
#include <hip/hip_runtime.h>
#include <stdint.h>

typedef unsigned long long u64;
typedef unsigned int u32;

#define VOX     32768      // 32*32*32
#define KCAP    512        // candidate cap (matches reference K; npos <= NPTS=400)
#define MAXEV   100        // max_events
#define BPF     8          // stage blocks per frame
#define THREADS 256
#define SEGCAP  512        // per-(frame,chunk) candidate segment capacity
#define HASHN   1024       // LDS hash map entries (4 KB)
#define HEMPTY  0xFFFFFFFFu

// dist < 2.0 on integer coords  <=>  Chebyshev distance <= 1 (3x3x3 cube)
// Priority key: (float_bits(val) << 32) | ~vox  — vals > 0 so float bits are
// monotone; higher val => bigger key; tie => lower vox => bigger key.
// hp(i over t) <=> key[i] > key[t]. Keys unique (voxels unique).
//
// R8 post-mortem: nontemporal ld/st REGRESSED (+9 us) — input is L2/L3-hot
// from the harness restore. Keep cached accesses.
//
// ws layout: gcnt int[256*8] @0, gnz int[256*8] @65536,
//            grec u64[256*8*SEGCAP] @131072 (8 MB), done int[256] @8519680.
// Only done[] needs zeroing (1 KB memset); everything else rewritten.

__global__ __launch_bounds__(THREADS) void fused_kernel(
    const float* __restrict__ x, float* __restrict__ out,
    int* __restrict__ gcnt, int* __restrict__ gnz, u64* __restrict__ grec,
    int* __restrict__ done)
{
    const int bid = blockIdx.x;
    const int f   = bid / BPF;
    const int c   = bid % BPF;
    const int tid = threadIdx.x;

    __shared__ u64   sbuf[SEGCAP];       // stage candidate keys (4 KB)
    __shared__ u64   skey[KCAP];         // packed keys, NMS phase (4 KB)
    __shared__ u32   hmap[HASHN];        // voxel->slot hash map (4 KB)
    __shared__ short srank[KCAP];        // (1 KB)
    __shared__ unsigned char status[KCAP];  // 0 undec, 1 kept, 2 suppressed
    __shared__ int s_off[BPF + 1];
    __shared__ int s_cnt, s_nz, s_old, s_nkept, s_undec;

    // ======================= STAGE PHASE (all blocks) =======================
    if (tid == 0) { s_cnt = 0; s_nz = 0; }
    __syncthreads();

    // issue all energy loads first (4 float4 / thread)
    const float4* e4 = (const float4*)(x + (size_t)f * 2 * VOX) + c * (VOX / BPF / 4);
    float4 v[(VOX / BPF / 4) / THREADS];
    #pragma unroll
    for (int h = 0; h < (VOX / BPF / 4) / THREADS; ++h)
        v[h] = e4[tid + h * THREADS];

    // zero-fill this block's slice of the [2,V] output while loads fly
    {
        float4* o4 = (float4*)(out + (size_t)f * 2 * VOX) + c * (2 * VOX / BPF / 4);
        const float4 z = make_float4(0.f, 0.f, 0.f, 0.f);
        #pragma unroll
        for (int h = 0; h < (2 * VOX / BPF / 4) / THREADS; ++h)
            o4[tid + h * THREADS] = z;
    }

    // scan loaded values for positives
    bool anynz = false;
    #pragma unroll
    for (int h = 0; h < (VOX / BPF / 4) / THREADS; ++h) {
        int li = tid + h * THREADS;
        int vbase = c * (VOX / BPF) + li * 4;
        float vv[4] = {v[h].x, v[h].y, v[h].z, v[h].w};
        #pragma unroll
        for (int cc = 0; cc < 4; ++cc) {
            float val = vv[cc];
            anynz |= (val != 0.f);
            if (val > 0.f) {
                int slot = atomicAdd(&s_cnt, 1);          // LDS atomic
                if (slot < SEGCAP) {
                    int vox = vbase + cc;
                    sbuf[slot] = ((u64)__float_as_uint(val) << 32) | (u64)(~(u32)vox);
                }
            }
        }
    }
    if (anynz) s_nz = 1;
    __syncthreads();

    const int cnt = min(s_cnt, SEGCAP);
    for (int i = tid; i < cnt; i += THREADS)
        grec[((size_t)f * BPF + c) * SEGCAP + i] = sbuf[i];
    if (tid == 0) {
        gcnt[f * BPF + c] = cnt;
        gnz [f * BPF + c] = s_nz;
    }

    // release: make this block's grec/gcnt/gnz/out stores device-visible,
    // then count in. Last block of the frame proceeds to NMS.
    __threadfence();
    __syncthreads();
    if (tid == 0) s_old = atomicAdd(&done[f], 1);
    __syncthreads();
    if (s_old != BPF - 1) return;
    __threadfence();   // acquire: see the other 7 blocks' writes

    // ================== NMS PHASE (last block per frame) ===================
    if (tid == 0) {
        int acc = 0, nz = 0;
        #pragma unroll
        for (int cc = 0; cc < BPF; ++cc) {
            s_off[cc] = acc;
            acc += gcnt[f * BPF + cc];
            nz  |= gnz [f * BPF + cc];
        }
        s_off[BPF] = acc;
        s_nz = nz;
        s_nkept = 0;
    }
    for (int i = tid; i < HASHN; i += THREADS) hmap[i] = HEMPTY;
    __syncthreads();

    const int n = min(s_off[BPF], KCAP);

    if (s_nz == 0) {   // empty frame: pass input through (never hot here)
        const float4* x4 = (const float4*)(x + (size_t)f * 2 * VOX);
        float4*       o4 = (float4*)(out + (size_t)f * 2 * VOX);
        for (int i = tid; i < 2 * VOX / 4; i += THREADS) o4[i] = x4[i];
        return;
    }

    // gather segments into packed key array + hash map
    for (int o = tid; o < n; o += THREADS) {
        int c2 = 0;
        #pragma unroll
        for (int cc = 0; cc < BPF; ++cc)
            if (o >= s_off[cc]) c2 = cc;
        u64 k = grec[((size_t)f * BPF + c2) * SEGCAP + (o - s_off[c2])];
        skey[o] = k;
        u32 vox = (~(u32)k) & (VOX - 1);
        u32 ent = (vox << 16) | (u32)o;
        u32 h   = (vox * 2654435761u) >> 22;
        while (atomicCAS(&hmap[h], HEMPTY, ent) != HEMPTY) h = (h + 1) & (HASHN - 1);
    }
    __syncthreads();

    // rank (broadcast loop) + status init
    for (int o = tid; o < n; o += THREADS) {
        const u64 kt = skey[o];
        int r = 0;
        #pragma unroll 8
        for (int i = 0; i < n; ++i)
            r += (skey[i] > kt);
        srank[o]  = (short)r;
        status[o] = 0;
    }
    __syncthreads();

    // monotone label propagation; neighbors re-probed via hash (rounds are few)
    for (int round = 0; round < KCAP; ++round) {
        if (tid == 0) s_undec = 0;
        __syncthreads();
        for (int o = tid; o < n; o += THREADS) {
            if (status[o] != 0) continue;
            const u64 kt = skey[o];
            const int vox = (int)(~(u32)kt) & (VOX - 1);
            const int zt = vox >> 10, yt = (vox >> 5) & 31, xt = vox & 31;
            bool anyKept = false, anyUndec = false;
            #pragma unroll
            for (int dz = -1; dz <= 1; ++dz) {
                int z = zt + dz; if ((unsigned)z >= 32) continue;
                #pragma unroll
                for (int dy = -1; dy <= 1; ++dy) {
                    int yy = yt + dy; if ((unsigned)yy >= 32) continue;
                    #pragma unroll
                    for (int dx = -1; dx <= 1; ++dx) {
                        int xx = xt + dx; if ((unsigned)xx >= 32) continue;
                        int nv = (z << 10) | (yy << 5) | xx;
                        if (nv == vox) continue;
                        u32 h = ((u32)nv * 2654435761u) >> 22;
                        while (1) {
                            u32 ent = hmap[h];
                            if (ent == HEMPTY) break;
                            if ((int)(ent >> 16) == nv) {
                                int m = ent & 0xFFFF;
                                if (skey[m] > kt) {
                                    unsigned char s = status[m];
                                    anyKept  |= (s == 1);
                                    anyUndec |= (s == 0);
                                }
                                break;
                            }
                            h = (h + 1) & (HASHN - 1);
                        }
                    }
                }
            }
            if (anyKept)        status[o] = 2;
            else if (!anyUndec) status[o] = 1;
            else                s_undec = 1;     // benign race
        }
        __syncthreads();
        if (s_undec == 0) break;
    }

    // count kept, apply rank truncation, scatter survivors
    for (int o = tid; o < n; o += THREADS)
        if (status[o] == 1) atomicAdd(&s_nkept, 1);
    __syncthreads();
    const int nkept = s_nkept;
    for (int o = tid; o < n; o += THREADS) {
        if (status[o] == 1 && !(nkept > MAXEV && srank[o] >= MAXEV)) {
            u64 k = skey[o];
            int   vox = (int)(~(u32)k) & (VOX - 1);
            float val = __uint_as_float((u32)(k >> 32));
            float* of = out + (size_t)f * 2 * VOX;
            of[vox]       = val;                                   // exact energy
            of[VOX + vox] = x[(size_t)f * 2 * VOX + VOX + vox];    // exact magnitude
        }
    }
}

extern "C" void kernel_launch(void* const* d_in, const int* in_sizes, int n_in,
                              void* d_out, int out_size, void* d_ws, size_t ws_size,
                              hipStream_t stream) {
    const float* x = (const float*)d_in[0];
    float* out = (float*)d_out;
    int frames = in_sizes[0] / (2 * VOX);   // B*T = 256

    int* gcnt = (int*)d_ws;                                 // [256*8]
    int* gnz  = (int*)((char*)d_ws + 65536);                // [256*8]
    u64* grec = (u64*)((char*)d_ws + 131072);               // [256*8*SEGCAP]
    int* done = (int*)((char*)d_ws + 131072 + (size_t)256 * BPF * SEGCAP * 8);

    hipMemsetAsync(done, 0, frames * sizeof(int), stream);  // 1 KB
    fused_kernel<<<frames * BPF, THREADS, 0, stream>>>(x, out, gcnt, gnz, grec, done);
}

// Round 11
// 120.974 us; speedup vs baseline: 5.9578x; 5.9578x over previous
//
#include <hip/hip_runtime.h>
#include <stdint.h>

typedef unsigned long long u64;
typedef unsigned int u32;

#define VOX     32768      // 32*32*32
#define KCAP    512        // candidate cap (matches reference K; npos <= NPTS=400)
#define MAXEV   100        // max_events
#define NBRCAP  26         // geometric max conflicts per point (26-neighborhood)
#define K1_BPF  8          // stage blocks per frame
#define K1_THREADS 256
#define K2_THREADS 512
#define SEGCAP  512        // per-(frame,chunk) candidate segment capacity

// dist < 2.0 on integer coords  <=>  Chebyshev distance <= 1 (3x3x3 cube)
// Priority key: (float_bits(val) << 32) | ~vox  — vals > 0 so float bits are
// monotone; higher val => bigger key; tie => lower vox => bigger key.
// hp(i over t) <=> key[i] > key[t]. Keys unique (voxels unique).
//
// Session pricing of alternatives (do not retry):
//  - R8: nontemporal ld/st => +9 us (input is L2/L3-hot from harness restore).
//  - R10: single-kernel fusion w/ done[f] counter + __threadfence() => 6x
//    regression (per-block device fence = L2 writeback/invalidate; 2048 of
//    them serialize the store stream to 130 GB/s). Cross-block handoff on
//    MI355X costs more than the ~7 us it could reclaim.
//  - R5: per-wave global atomics on packed counters => 6x regression
//    (cacheline ping-pong across XCDs). Private segments + unconditional
//    stores (below) is the right shape.
//
// ws layout (no zeroing needed — every word rewritten each launch):
//   gcnt int[256*8]  @ 0        : per-(frame,chunk) candidate count
//   gnz  int[256*8]  @ 65536    : per-(frame,chunk) any-nonzero flag
//   grec u64[256*8*SEGCAP] @ 131072 : per-(frame,chunk) key segments (8 MB)

// ---------------------------------------------------------------------------
// Kernel 1: pure streaming, zero inter-block communication. Energy loads are
// issued FIRST so their latency overlaps the zero-fill store stream; then
// collect positives in LDS and flush to a PRIVATE global segment.
// ---------------------------------------------------------------------------
__global__ __launch_bounds__(K1_THREADS) void stage_kernel(
    const float* __restrict__ x, float* __restrict__ out,
    int* __restrict__ gcnt, int* __restrict__ gnz, u64* __restrict__ grec)
{
    const int bid = blockIdx.x;
    const int f   = bid / K1_BPF;
    const int c   = bid % K1_BPF;
    const int tid = threadIdx.x;

    __shared__ u64 sbuf[SEGCAP];    // per-block candidate keys (4 KB)
    __shared__ int s_cnt, s_nz;

    if (tid == 0) { s_cnt = 0; s_nz = 0; }
    __syncthreads();

    // issue all energy loads first (4 float4 / thread)
    const float4* e4 = (const float4*)(x + (size_t)f * 2 * VOX) + c * (VOX / K1_BPF / 4);
    float4 v[(VOX / K1_BPF / 4) / K1_THREADS];
    #pragma unroll
    for (int h = 0; h < (VOX / K1_BPF / 4) / K1_THREADS; ++h)
        v[h] = e4[tid + h * K1_THREADS];

    // zero-fill this block's slice of the [2,V] output (8 float4 / thread)
    // while the loads are in flight
    {
        float4* o4 = (float4*)(out + (size_t)f * 2 * VOX) + c * (2 * VOX / K1_BPF / 4);
        const float4 z = make_float4(0.f, 0.f, 0.f, 0.f);
        #pragma unroll
        for (int h = 0; h < (2 * VOX / K1_BPF / 4) / K1_THREADS; ++h)
            o4[tid + h * K1_THREADS] = z;
    }

    // scan the loaded values for positives
    bool anynz = false;
    #pragma unroll
    for (int h = 0; h < (VOX / K1_BPF / 4) / K1_THREADS; ++h) {
        int li = tid + h * K1_THREADS;                    // local float4 index
        int vbase = c * (VOX / K1_BPF) + li * 4;          // voxel of component 0
        float vv[4] = {v[h].x, v[h].y, v[h].z, v[h].w};
        #pragma unroll
        for (int cc = 0; cc < 4; ++cc) {
            float val = vv[cc];
            anynz |= (val != 0.f);
            if (val > 0.f) {                              // rare (~6/thread)
                int slot = atomicAdd(&s_cnt, 1);          // LDS atomic: cheap
                if (slot < SEGCAP) {
                    int vox = vbase + cc;
                    sbuf[slot] = ((u64)__float_as_uint(val) << 32) | (u64)(~(u32)vox);
                }
            }
        }
    }
    if (anynz) s_nz = 1;                                  // benign race
    __syncthreads();

    const int cnt = min(s_cnt, SEGCAP);
    // flush to private segment + unconditional count/flag stores (no atomics)
    for (int i = tid; i < cnt; i += K1_THREADS)
        grec[((size_t)f * K1_BPF + c) * SEGCAP + i] = sbuf[i];
    if (tid == 0) {
        gcnt[f * K1_BPF + c] = cnt;
        gnz [f * K1_BPF + c] = s_nz;
    }
}

// ---------------------------------------------------------------------------
// Kernel 2: per-frame NMS on the 8 gathered segments + direct scatter of
// survivors onto the pre-zeroed output. 1 block/frame, LDS-resident.
// ---------------------------------------------------------------------------
__global__ __launch_bounds__(K2_THREADS) void nms_scatter_kernel(
    const float* __restrict__ x, float* __restrict__ out,
    const int* __restrict__ gcnt, const int* __restrict__ gnz,
    const u64* __restrict__ grec)
{
    const int f    = blockIdx.x;
    const int tid  = threadIdx.x;
    const int wave = tid >> 6;
    const int lane = tid & 63;

    __shared__ unsigned short smap[VOX];            // voxel -> slot (0xFFFF none), 64 KB
    __shared__ u64   skey[KCAP];
    __shared__ short srank[KCAP];
    __shared__ unsigned char status[KCAP];          // 0 undecided, 1 kept, 2 suppressed
    __shared__ unsigned short pnbr[KCAP * NBRCAP];  // higher-priority conflicts
    __shared__ int s_off[K1_BPF + 1];
    __shared__ int s_nz, s_nkept, s_undec;

    // gather segment counts -> offsets (thread 0, 8 iterations: trivial)
    if (tid == 0) {
        int acc = 0, nz = 0;
        #pragma unroll
        for (int c = 0; c < K1_BPF; ++c) {
            s_off[c] = acc;
            acc += gcnt[f * K1_BPF + c];
            nz  |= gnz [f * K1_BPF + c];
        }
        s_off[K1_BPF] = acc;
        s_nz = nz;
        s_nkept = 0;
    }
    {   // init voxel map (concurrent with thread-0 scan)
        u32* m32 = (u32*)smap;
        #pragma unroll
        for (int h = 0; h < VOX / 2 / K2_THREADS; ++h)
            m32[tid + h * K2_THREADS] = 0xFFFFFFFFu;
    }
    __syncthreads();

    const int n = min(s_off[K1_BPF], KCAP);

    if (s_nz == 0) {
        // empty frame: pass input through (overwrites the zero-fill)
        const float4* x4 = (const float4*)(x + (size_t)f * 2 * VOX);
        float4*       o4 = (float4*)(out + (size_t)f * 2 * VOX);
        for (int i = tid; i < 2 * VOX / 4; i += K2_THREADS) o4[i] = x4[i];
        return;
    }

    // wave w gathers segment w into the packed key array + voxel map
    {
        const int cnt  = s_off[wave + 1] - s_off[wave];
        const int base = s_off[wave];
        const u64* seg = grec + ((size_t)f * K1_BPF + wave) * SEGCAP;
        for (int i = lane; i < cnt; i += 64) {
            int o = base + i;
            if (o < KCAP) {
                u64 k = seg[i];
                skey[o] = k;
                smap[(int)(~(u32)k) & (VOX - 1)] = (unsigned short)o;
            }
        }
    }
    __syncthreads();

    // rank (pure broadcast loop, pipelines) + neighbors via 26 map probes
    int pcnt = 0;
    if (tid < n) {
        const u64 kt = skey[tid];
        int rank = 0;
        #pragma unroll 8
        for (int i = 0; i < n; ++i)
            rank += (skey[i] > kt);
        srank[tid] = (short)rank;

        const int vox = (int)(~(u32)kt) & (VOX - 1);
        const int zt = vox >> 10, yt = (vox >> 5) & 31, xt = vox & 31;
        #pragma unroll
        for (int dz = -1; dz <= 1; ++dz) {
            int z = zt + dz; if ((unsigned)z >= 32) continue;
            #pragma unroll
            for (int dy = -1; dy <= 1; ++dy) {
                int yy = yt + dy; if ((unsigned)yy >= 32) continue;
                #pragma unroll
                for (int dx = -1; dx <= 1; ++dx) {
                    int xx = xt + dx; if ((unsigned)xx >= 32) continue;
                    int nv = (z << 10) | (yy << 5) | xx;
                    if (nv == vox) continue;
                    unsigned short m = smap[nv];
                    if (m != 0xFFFFu && skey[m] > kt)
                        pnbr[tid * NBRCAP + pcnt++] = m;
                }
            }
        }
        status[tid] = (pcnt == 0) ? (unsigned char)1 : (unsigned char)0;
    }
    __syncthreads();

    // parallel greedy resolution (monotone label propagation; converges in
    // <= n rounds since the highest-priority undecided point always resolves)
    for (int round = 0; round < KCAP; ++round) {
        if (tid == 0) s_undec = 0;
        __syncthreads();
        if (tid < n && status[tid] == 0) {
            bool anyKept = false, anyUndec = false;
            for (int p = 0; p < pcnt; ++p) {
                unsigned char s = status[pnbr[tid * NBRCAP + p]];
                anyKept  |= (s == 1);
                anyUndec |= (s == 0);
            }
            if (anyKept)        status[tid] = 2;
            else if (!anyUndec) status[tid] = 1;
            else                s_undec = 1;        // benign race: all write 1
        }
        __syncthreads();
        if (s_undec == 0) break;
    }

    // count kept, apply rank truncation, scatter survivors to output
    if (tid < n && status[tid] == 1) atomicAdd(&s_nkept, 1);
    __syncthreads();
    const int nkept = s_nkept;
    if (tid < n && status[tid] == 1 &&
        !(nkept > MAXEV && srank[tid] >= MAXEV)) {
        u64 k = skey[tid];
        int   vox = (int)(~(u32)k) & (VOX - 1);
        float val = __uint_as_float((u32)(k >> 32));
        float* of = out + (size_t)f * 2 * VOX;
        of[vox]       = val;                                   // exact energy copy
        of[VOX + vox] = x[(size_t)f * 2 * VOX + VOX + vox];    // exact magnitude copy
    }
}

extern "C" void kernel_launch(void* const* d_in, const int* in_sizes, int n_in,
                              void* d_out, int out_size, void* d_ws, size_t ws_size,
                              hipStream_t stream) {
    const float* x = (const float*)d_in[0];
    float* out = (float*)d_out;
    int frames = in_sizes[0] / (2 * VOX);   // B*T = 256

    int* gcnt = (int*)d_ws;                             // [256*8]
    int* gnz  = (int*)((char*)d_ws + 65536);            // [256*8]
    u64* grec = (u64*)((char*)d_ws + 131072);           // [256*8*SEGCAP]

    stage_kernel<<<frames * K1_BPF, K1_THREADS, 0, stream>>>(x, out, gcnt, gnz, grec);
    nms_scatter_kernel<<<frames, K2_THREADS, 0, stream>>>(x, out, gcnt, gnz, grec);
}